// Round 5
// baseline (419.853 us; speedup 1.0000x reference)
//
#include <hip/hip_runtime.h>

typedef _Float16 half8   __attribute__((ext_vector_type(8)));
typedef float    floatx16 __attribute__((ext_vector_type(16)));

#define LOG2E 1.44269504088896340736f
#define NQ 2048
#define NK 2048
#define DIM 512
#define KT 32
#define NTILES 64

__device__ __forceinline__ unsigned pk2(float a, float b) {
    typedef __fp16 fp16x2 __attribute__((ext_vector_type(2)));
    fp16x2 h = __builtin_amdgcn_cvt_pkrtz(a, b);
    return __builtin_bit_cast(unsigned, h);
}

// sKr[b]: row-major K tile, row*512 + ((g ^ key(row))<<3), g = d>>3,
//         key(r) = ((r&3)<<1)|((r>>2)&1). Conflict-free b128 W/R.
// sKt[b]: K^T slot layout: dp=d>>1, slot=((dp&3)<<6)|(dp>>2), 72 f16/slot;
//         k-octet g stored at ((g^(dp&3))<<4) + ((d&1)<<3). Conflict-free b128 W/R.
// sSx:    partial-S exchange, per-lane stride 20 floats (80 B) -> 8 distinct
//         bank-quads per 8 lanes, conflict-free b128.

__global__ __launch_bounds__(512, 2)
void attn_fa(const float* __restrict__ Qg, const float* __restrict__ Kg,
             float* __restrict__ Og)
{
    __shared__ __align__(16) _Float16 sKr[2][KT * 512];   // 2 x 32768 B
    __shared__ __align__(16) _Float16 sKt[2][256 * 72];   // 2 x 36864 B
    __shared__ __align__(16) float    sSx[4 * 64 * 20];   // 20480 B (tot 159744)

    const int tid  = threadIdx.x;
    const int lane = tid & 63;
    const int wave = tid >> 6;        // 0..3 consumers, 4..7 producers
    const int hf   = lane >> 5;
    const int l31  = lane & 31;

    const int batch = blockIdx.x & 7;     // batch -> XCD (K L2-resident)
    const int qtile = blockIdx.x >> 3;    // 0..31, 64 q each

    const bool consumer = (wave < 4);
    const int s = wave & 1;               // q-strip (32 q)
    const int h = (wave >> 1) & 1;        // d-half for QK contraction & PV output
    const int q = qtile * 64 + s * 32 + l31;

    half8 qf[16];
    floatx16 acc[8];
    float m_run = -INFINITY, l_run = 0.f;
    float rv[8][8];                        // producer staging regs
    const int pidx = wave - 4;

    if (consumer) {
        // Q B-frags: qf[ds][j] = Q[q][h*256 + ds*16 + hf*8 + j]
        const float* qp = Qg + ((size_t)batch * NQ + q) * DIM + h * 256 + hf * 8;
        #pragma unroll
        for (int ds = 0; ds < 16; ++ds) {
            float4 u0 = *(const float4*)(qp + ds * 16);
            float4 u1 = *(const float4*)(qp + ds * 16 + 4);
            union { unsigned u[4]; half8 v; } t;
            t.u[0] = pk2(u0.x, u0.y); t.u[1] = pk2(u0.z, u0.w);
            t.u[2] = pk2(u1.x, u1.y); t.u[3] = pk2(u1.z, u1.w);
            qf[ds] = t.v;
        }
        #pragma unroll
        for (int mt = 0; mt < 8; ++mt)
            #pragma unroll
            for (int r = 0; r < 16; ++r) acc[mt][r] = 0.f;
    } else {
        // stage tile 0 into buf 0
        const float* kp = Kg + ((size_t)batch * NK + pidx * 8) * DIM + lane * 8;
        #pragma unroll
        for (int kk = 0; kk < 8; ++kk) {
            float4 f0 = *(const float4*)(kp + kk * DIM);
            float4 f1 = *(const float4*)(kp + kk * DIM + 4);
            rv[kk][0]=f0.x; rv[kk][1]=f0.y; rv[kk][2]=f0.z; rv[kk][3]=f0.w;
            rv[kk][4]=f1.x; rv[kk][5]=f1.y; rv[kk][6]=f1.z; rv[kk][7]=f1.w;
        }
        #pragma unroll
        for (int kk = 0; kk < 8; ++kk) {
            const int row = pidx * 8 + kk;
            const int key = ((row & 3) << 1) | ((row >> 2) & 1);
            uint4 w;
            w.x = pk2(rv[kk][0], rv[kk][1]); w.y = pk2(rv[kk][2], rv[kk][3]);
            w.z = pk2(rv[kk][4], rv[kk][5]); w.w = pk2(rv[kk][6], rv[kk][7]);
            *(uint4*)&sKr[0][row * 512 + ((lane ^ key) << 3)] = w;
        }
        #pragma unroll
        for (int dd = 0; dd < 8; ++dd) {
            const int pp = dd >> 1;
            uint4 w;
            w.x = pk2(rv[0][dd], rv[1][dd]); w.y = pk2(rv[2][dd], rv[3][dd]);
            w.z = pk2(rv[4][dd], rv[5][dd]); w.w = pk2(rv[6][dd], rv[7][dd]);
            *(uint4*)&sKt[0][((pp << 6) | lane) * 72 + ((pidx ^ pp) << 4) + ((dd & 1) << 3)] = w;
        }
    }

    const int keyr = ((l31 & 3) << 1) | ((l31 >> 2) & 1);

    for (int t = 0; t < NTILES; ++t) {
        const int b = t & 1;
        __syncthreads();                       // buf[b] staged; prior reads done

        floatx16 sv;
        if (consumer) {
            // ---- partial S^T over d-half h: 16 MFMA in 2 chains ----
            const _Float16* kr = &sKr[b][l31 * 512];
            floatx16 s0, s1;
            #pragma unroll
            for (int r = 0; r < 16; ++r) { s0[r] = 0.f; s1[r] = 0.f; }
            #pragma unroll
            for (int ds = 0; ds < 16; ds += 2) {
                const int g0 = h * 32 + ds * 2 + hf;
                half8 a0 = *(const half8*)&kr[(g0 ^ keyr) << 3];
                half8 a1 = *(const half8*)&kr[((g0 + 2) ^ keyr) << 3];
                s0 = __builtin_amdgcn_mfma_f32_32x32x16_f16(a0, qf[ds], s0, 0, 0, 0);
                s1 = __builtin_amdgcn_mfma_f32_32x32x16_f16(a1, qf[ds + 1], s1, 0, 0, 0);
            }
            sv = s0 + s1;
            float* sx = &sSx[wave * 1280 + lane * 20];
            float4 t0, t1, t2, t3;
            t0.x=sv[0]; t0.y=sv[1]; t0.z=sv[2]; t0.w=sv[3];
            t1.x=sv[4]; t1.y=sv[5]; t1.z=sv[6]; t1.w=sv[7];
            t2.x=sv[8]; t2.y=sv[9]; t2.z=sv[10]; t2.w=sv[11];
            t3.x=sv[12]; t3.y=sv[13]; t3.z=sv[14]; t3.w=sv[15];
            *(float4*)(sx + 0) = t0; *(float4*)(sx + 4)  = t1;
            *(float4*)(sx + 8) = t2; *(float4*)(sx + 12) = t3;
        } else if (t + 1 < NTILES) {
            const float* kp = Kg + ((size_t)batch * NK + (t + 1) * KT + pidx * 8) * DIM + lane * 8;
            #pragma unroll
            for (int kk = 0; kk < 8; ++kk) {
                float4 f0 = *(const float4*)(kp + kk * DIM);
                float4 f1 = *(const float4*)(kp + kk * DIM + 4);
                rv[kk][0]=f0.x; rv[kk][1]=f0.y; rv[kk][2]=f0.z; rv[kk][3]=f0.w;
                rv[kk][4]=f1.x; rv[kk][5]=f1.y; rv[kk][6]=f1.z; rv[kk][7]=f1.w;
            }
        }

        __syncthreads();                       // sSx ready / QK reads of buf done

        if (consumer) {
            // ---- combine with partner d-half ----
            const float* px = &sSx[(wave ^ 2) * 1280 + lane * 20];
            float4 r0 = *(const float4*)(px + 0), r1 = *(const float4*)(px + 4);
            float4 r2 = *(const float4*)(px + 8), r3 = *(const float4*)(px + 12);
            sv[0]+=r0.x; sv[1]+=r0.y; sv[2]+=r0.z; sv[3]+=r0.w;
            sv[4]+=r1.x; sv[5]+=r1.y; sv[6]+=r1.z; sv[7]+=r1.w;
            sv[8]+=r2.x; sv[9]+=r2.y; sv[10]+=r2.z; sv[11]+=r2.w;
            sv[12]+=r3.x; sv[13]+=r3.y; sv[14]+=r3.z; sv[15]+=r3.w;

            // ---- online softmax (q = l31 lane-local; halves reduce via xor32) ----
            float mx = sv[0];
            #pragma unroll
            for (int r = 1; r < 16; ++r) mx = fmaxf(mx, sv[r]);
            mx = fmaxf(mx, __shfl_xor(mx, 32));
            const float m_new = fmaxf(m_run, mx);
            const float al = exp2f((m_run - m_new) * LOG2E);
            float p[16];
            #pragma unroll
            for (int r = 0; r < 16; ++r) p[r] = exp2f((sv[r] - m_new) * LOG2E);
            float ls = 0.f;
            #pragma unroll
            for (int r = 0; r < 16; ++r) ls += p[r];
            ls += __shfl_xor(ls, 32);
            l_run = l_run * al + ls;
            m_run = m_new;
            if (__any(al != 1.0f)) {
                #pragma unroll
                for (int mt = 0; mt < 8; ++mt) acc[mt] = acc[mt] * al;
            }

            // ---- P^T B-frags: B[k=kstep*16+hf*8+j][q=l31] via xor32 shuffles ----
            unsigned A0 = pk2(p[0],  p[1]),  A1 = pk2(p[2],  p[3]);
            unsigned B0 = pk2(p[4],  p[5]),  B1 = pk2(p[6],  p[7]);
            unsigned C0 = pk2(p[8],  p[9]),  C1 = pk2(p[10], p[11]);
            unsigned D0 = pk2(p[12], p[13]), D1 = pk2(p[14], p[15]);
            unsigned A0x = (unsigned)__shfl_xor((int)A0, 32);
            unsigned A1x = (unsigned)__shfl_xor((int)A1, 32);
            unsigned B0x = (unsigned)__shfl_xor((int)B0, 32);
            unsigned B1x = (unsigned)__shfl_xor((int)B1, 32);
            unsigned C0x = (unsigned)__shfl_xor((int)C0, 32);
            unsigned C1x = (unsigned)__shfl_xor((int)C1, 32);
            unsigned D0x = (unsigned)__shfl_xor((int)D0, 32);
            unsigned D1x = (unsigned)__shfl_xor((int)D1, 32);
            union { unsigned u[4]; half8 v; } pf0, pf1;
            if (hf == 0) {
                pf0.u[0]=A0;  pf0.u[1]=A1;  pf0.u[2]=A0x; pf0.u[3]=A1x;
                pf1.u[0]=C0;  pf1.u[1]=C1;  pf1.u[2]=C0x; pf1.u[3]=C1x;
            } else {
                pf0.u[0]=B0x; pf0.u[1]=B1x; pf0.u[2]=B0;  pf0.u[3]=B1;
                pf1.u[0]=D0x; pf1.u[1]=D1x; pf1.u[2]=D0;  pf1.u[3]=D1;
            }

            // ---- O^T += K^T . P^T over d-half h ----
            #pragma unroll
            for (int mt = 0; mt < 8; ++mt) {
                const int drow = h * 256 + mt * 32 + l31;
                const int dp = drow >> 1;
                const _Float16* tb = &sKt[b][(((dp & 3) << 6) | (dp >> 2)) * 72 + ((drow & 1) << 3)];
                half8 a0 = *(const half8*)&tb[(hf ^ (dp & 3)) << 4];
                half8 a1 = *(const half8*)&tb[((2 + hf) ^ (dp & 3)) << 4];
                acc[mt] = __builtin_amdgcn_mfma_f32_32x32x16_f16(a0, pf0.v, acc[mt], 0, 0, 0);
                acc[mt] = __builtin_amdgcn_mfma_f32_32x32x16_f16(a1, pf1.v, acc[mt], 0, 0, 0);
            }
        } else if (t + 1 < NTILES) {
            const int b2 = (t + 1) & 1;
            #pragma unroll
            for (int kk = 0; kk < 8; ++kk) {
                const int row = pidx * 8 + kk;
                const int key = ((row & 3) << 1) | ((row >> 2) & 1);
                uint4 w;
                w.x = pk2(rv[kk][0], rv[kk][1]); w.y = pk2(rv[kk][2], rv[kk][3]);
                w.z = pk2(rv[kk][4], rv[kk][5]); w.w = pk2(rv[kk][6], rv[kk][7]);
                *(uint4*)&sKr[b2][row * 512 + ((lane ^ key) << 3)] = w;
            }
            #pragma unroll
            for (int dd = 0; dd < 8; ++dd) {
                const int pp = dd >> 1;
                uint4 w;
                w.x = pk2(rv[0][dd], rv[1][dd]); w.y = pk2(rv[2][dd], rv[3][dd]);
                w.z = pk2(rv[4][dd], rv[5][dd]); w.w = pk2(rv[6][dd], rv[7][dd]);
                *(uint4*)&sKt[b2][((pp << 6) | lane) * 72 + ((pidx ^ pp) << 4) + ((dd & 1) << 3)] = w;
            }
        }
    }

    if (consumer) {
        const float inv = 1.f / l_run;
        float* op = Og + ((size_t)batch * NQ + q) * DIM + h * 256 + hf * 4;
        #pragma unroll
        for (int mt = 0; mt < 8; ++mt) {
            #pragma unroll
            for (int r2 = 0; r2 < 4; ++r2) {
                float4 v;
                v.x = acc[mt][4*r2+0] * inv; v.y = acc[mt][4*r2+1] * inv;
                v.z = acc[mt][4*r2+2] * inv; v.w = acc[mt][4*r2+3] * inv;
                *(float4*)(op + mt * 32 + r2 * 8) = v;
            }
        }
    }
}

extern "C" void kernel_launch(void* const* d_in, const int* in_sizes, int n_in,
                              void* d_out, int out_size, void* d_ws, size_t ws_size,
                              hipStream_t stream) {
    (void)in_sizes; (void)n_in; (void)d_ws; (void)ws_size; (void)out_size;
    const float* Q = (const float*)d_in[0];
    const float* K = (const float*)d_in[1];
    float* O = (float*)d_out;
    dim3 grid(256), block(512);
    hipLaunchKernelGGL(attn_fa, grid, block, 0, stream, Q, K, O);
}

// Round 6
// 295.769 us; speedup vs baseline: 1.4195x; 1.4195x over previous
//
#include <hip/hip_runtime.h>

typedef _Float16 half8  __attribute__((ext_vector_type(8)));
typedef float    floatx4 __attribute__((ext_vector_type(4)));

#define LOG2E 1.44269504088896340736f
#define NQ  2048
#define NK  2048
#define DIM 512
#define KT  32

__device__ __forceinline__ unsigned pk2(float a, float b) {
    typedef __fp16 fp16x2 __attribute__((ext_vector_type(2)));
    fp16x2 h = __builtin_amdgcn_cvt_pkrtz(a, b);
    return __builtin_bit_cast(unsigned, h);
}

__device__ __forceinline__ void gld_lds16(const _Float16* g, _Float16* l) {
    __builtin_amdgcn_global_load_lds(
        (const __attribute__((address_space(1))) unsigned int*)g,
        (__attribute__((address_space(3))) unsigned int*)l, 16, 0, 0);
}

// ws layout: wsR = 8x64 tiles x 16384 f16 (32 KB) = byte-image of sKr swizzle:
//   elem (k,g-octet) at k*512 + ((g ^ key(k))<<3), key(k)=((k&3)<<1)|((k>>2)&1)
// wsT = 8x64 tiles x 18432 f16 (36 KB) = byte-image of sKt slot layout:
//   elem (d,k) at slot*72 + ((g^(dp&3))<<4) + ((d&1)<<3) + (k&7),
//   dp=d>>1, slot=((dp&3)<<6)|(dp>>2), g=k>>3.   (Both layouts HW-verified R4/R5.)

__global__ __launch_bounds__(256, 1)
void pack_k(const float* __restrict__ Kg, _Float16* __restrict__ wsR,
            _Float16* __restrict__ wsT)
{
    const int bt = blockIdx.x;           // b*64 + tile
    const int b  = bt >> 6, t = bt & 63;
    const float* kp = Kg + ((size_t)b * NK + t * KT) * DIM;
    _Float16* rImg = wsR + (size_t)bt * 16384;
    _Float16* tImg = wsT + (size_t)bt * 18432;
    #pragma unroll
    for (int i = 0; i < 8; ++i) {
        const int e  = threadIdx.x + i * 256;   // 0..2047
        const int k  = e >> 6, go = e & 63;
        float4 f0 = *(const float4*)(kp + k * DIM + go * 8);
        float4 f1 = *(const float4*)(kp + k * DIM + go * 8 + 4);
        union { uint4 w; _Float16 h[8]; } u;
        u.w.x = pk2(f0.x, f0.y); u.w.y = pk2(f0.z, f0.w);
        u.w.z = pk2(f1.x, f1.y); u.w.w = pk2(f1.z, f1.w);
        const int key = ((k & 3) << 1) | ((k >> 2) & 1);
        *(uint4*)&rImg[k * 512 + ((go ^ key) << 3)] = u.w;
        #pragma unroll
        for (int j = 0; j < 8; ++j) {
            const int d = go * 8 + j, dp = d >> 1;
            const int slot = ((dp & 3) << 6) | (dp >> 2);
            tImg[slot * 72 + (((k >> 3) ^ (dp & 3)) << 4) + ((d & 1) << 3) + (k & 7)] = u.h[j];
        }
    }
}

__global__ __launch_bounds__(256, 2)
void attn_fa(const float* __restrict__ Qg, const _Float16* __restrict__ wsR,
             const _Float16* __restrict__ wsT, float* __restrict__ Og)
{
    __shared__ __align__(16) _Float16 sKr[KT * 512];       // 32768 B
    __shared__ __align__(16) _Float16 sKt[256 * 72];       // 36864 B
    __shared__ __align__(16) float    sSx[4 * 2 * 64 * 4]; //  8192 B => 77824 B

    const int tid  = threadIdx.x;
    const int lane = tid & 63;
    const int wave = tid >> 6;      // 0..3
    const int quad = lane >> 4;
    const int col  = lane & 15;
    const int wq   = wave & 1;      // q-strip (16 rows)
    const int wg   = wave >> 1;     // d-half
    const int dbase = wg * 256;

    const int batch = blockIdx.x & 7;     // batch -> XCD: images L2-resident
    const int qtile = blockIdx.x >> 3;    // 0..63
    const int qrow  = qtile * 32 + wq * 16 + col;

    // ---- Q fragments (B-layout): Q[q=col][d = dbase + dc*32 + quad*8 + j] ----
    const float* qp = Qg + ((size_t)batch * NQ + qrow) * DIM + dbase + quad * 8;
    half8 qf[8];
    #pragma unroll
    for (int dc = 0; dc < 8; ++dc) {
        float4 f0 = *(const float4*)(qp + dc * 32);
        float4 f1 = *(const float4*)(qp + dc * 32 + 4);
        union { unsigned u[4]; half8 h; } t;
        t.u[0] = pk2(f0.x, f0.y); t.u[1] = pk2(f0.z, f0.w);
        t.u[2] = pk2(f1.x, f1.y); t.u[3] = pk2(f1.z, f1.w);
        qf[dc] = t.h;
    }

    floatx4 acc[16];
    #pragma unroll
    for (int i = 0; i < 16; ++i) acc[i] = (floatx4){0.f, 0.f, 0.f, 0.f};

    float m_run = -INFINITY;
    float l_run = 0.f;

    const int keyc = ((col & 3) << 1) | ((col >> 2) & 1);

    for (int kt = 0; kt < NK / KT; ++kt) {
        // ---- async DMA stage of tile kt (lane-contiguous, conflict-free) ----
        {
            const size_t ib = (size_t)(batch * 64 + kt);
            const _Float16* gr = wsR + ib * 16384 + wave * 4096 + lane * 8;
            const _Float16* gt = wsT + ib * 18432 + wave * 4608 + lane * 8;
            _Float16* lr = &sKr[wave * 4096 + lane * 8];
            _Float16* lt = &sKt[wave * 4608 + lane * 8];
            #pragma unroll
            for (int i = 0; i < 8; ++i) gld_lds16(gr + i * 512, lr + i * 512);
            #pragma unroll
            for (int i = 0; i < 9; ++i) gld_lds16(gt + i * 512, lt + i * 512);
        }
        __syncthreads();   // drains vmcnt: tile staged

        // ---- partial S^T over this wave's d-half ----
        floatx4 s0 = {0.f, 0.f, 0.f, 0.f}, s1 = {0.f, 0.f, 0.f, 0.f};
        #pragma unroll
        for (int dc = 0; dc < 8; ++dc) {
            const int g = wg * 32 + dc * 4 + quad;
            const int off = ((g ^ keyc) << 3);
            half8 a0 = *(const half8*)&sKr[col * 512 + off];
            half8 a1 = *(const half8*)&sKr[(col + 16) * 512 + off];
            s0 = __builtin_amdgcn_mfma_f32_16x16x32_f16(a0, qf[dc], s0, 0, 0, 0);
            s1 = __builtin_amdgcn_mfma_f32_16x16x32_f16(a1, qf[dc], s1, 0, 0, 0);
        }

        // ---- combine d-half partials with partner wave (wave ^ 2) ----
        *(floatx4*)&sSx[((wave * 2 + 0) * 64 + lane) * 4] = s0;
        *(floatx4*)&sSx[((wave * 2 + 1) * 64 + lane) * 4] = s1;
        __syncthreads();
        {
            const int pw = wave ^ 2;
            s0 += *(const floatx4*)&sSx[((pw * 2 + 0) * 64 + lane) * 4];
            s1 += *(const floatx4*)&sSx[((pw * 2 + 1) * 64 + lane) * 4];
        }

        // ---- online softmax (q = col lane-local; reduce across quads) ----
        float mloc = fmaxf(fmaxf(fmaxf(s0[0], s0[1]), fmaxf(s0[2], s0[3])),
                           fmaxf(fmaxf(s1[0], s1[1]), fmaxf(s1[2], s1[3])));
        mloc = fmaxf(mloc, __shfl_xor(mloc, 16));
        mloc = fmaxf(mloc, __shfl_xor(mloc, 32));
        const float m_new = fmaxf(m_run, mloc);
        const float alpha = exp2f((m_run - m_new) * LOG2E);
        const float p0 = exp2f((s0[0] - m_new) * LOG2E);
        const float p1 = exp2f((s0[1] - m_new) * LOG2E);
        const float p2 = exp2f((s0[2] - m_new) * LOG2E);
        const float p3 = exp2f((s0[3] - m_new) * LOG2E);
        const float p4 = exp2f((s1[0] - m_new) * LOG2E);
        const float p5 = exp2f((s1[1] - m_new) * LOG2E);
        const float p6 = exp2f((s1[2] - m_new) * LOG2E);
        const float p7 = exp2f((s1[3] - m_new) * LOG2E);
        float sloc = ((p0 + p1) + (p2 + p3)) + ((p4 + p5) + (p6 + p7));
        sloc += __shfl_xor(sloc, 16);
        sloc += __shfl_xor(sloc, 32);
        l_run = l_run * alpha + sloc;
        m_run = m_new;

        #pragma unroll
        for (int i = 0; i < 16; ++i) acc[i] *= alpha;

        // ---- P fragment: B[k = quad*8 + j][q = col] via cross-quad shuffles ----
        const unsigned pk00 = pk2(p0, p1);
        const unsigned pk01 = pk2(p2, p3);
        const unsigned pk10 = pk2(p4, p5);
        const unsigned pk11 = pk2(p6, p7);
        const int srcA = col + ((quad & 1) << 5);
        const int srcB = srcA + 16;
        const unsigned a00 = (unsigned)__shfl((int)pk00, srcA);
        const unsigned a01 = (unsigned)__shfl((int)pk01, srcA);
        const unsigned a10 = (unsigned)__shfl((int)pk10, srcA);
        const unsigned a11 = (unsigned)__shfl((int)pk11, srcA);
        const unsigned b00 = (unsigned)__shfl((int)pk00, srcB);
        const unsigned b01 = (unsigned)__shfl((int)pk01, srcB);
        const unsigned b10 = (unsigned)__shfl((int)pk10, srcB);
        const unsigned b11 = (unsigned)__shfl((int)pk11, srcB);
        const bool hi2 = (quad >= 2);
        union { unsigned u[4]; half8 h; } pt;
        pt.u[0] = hi2 ? a10 : a00;
        pt.u[1] = hi2 ? a11 : a01;
        pt.u[2] = hi2 ? b10 : b00;
        pt.u[3] = hi2 ? b11 : b01;
        const half8 pf = pt.h;

        // ---- O^T += K^T . P^T over this wave's d-half (slot-layout A reads) ----
        #pragma unroll
        for (int dt = 0; dt < 16; ++dt) {
            const int drow = dbase + dt * 16 + col;
            const int dp = drow >> 1;
            const int off = (((dp & 3) << 6) | (dp >> 2)) * 72
                          + ((quad ^ (dp & 3)) << 4) + ((drow & 1) << 3);
            half8 af = *(const half8*)&sKt[off];
            acc[dt] = __builtin_amdgcn_mfma_f32_16x16x32_f16(af, pf, acc[dt], 0, 0, 0);
        }
        __syncthreads();   // all reads done before next tile's DMA overwrites
    }

    const float inv = 1.f / l_run;
    float* op = Og + ((size_t)batch * NQ + qrow) * DIM + dbase + quad * 4;
    #pragma unroll
    for (int dt = 0; dt < 16; ++dt) {
        floatx4 v = acc[dt] * inv;
        *(floatx4*)(op + dt * 16) = v;
    }
}

extern "C" void kernel_launch(void* const* d_in, const int* in_sizes, int n_in,
                              void* d_out, int out_size, void* d_ws, size_t ws_size,
                              hipStream_t stream) {
    (void)in_sizes; (void)n_in; (void)ws_size; (void)out_size;
    const float* Q = (const float*)d_in[0];
    const float* K = (const float*)d_in[1];
    float* O = (float*)d_out;
    _Float16* wsR = (_Float16*)d_ws;                       // 16,777,216 B
    _Float16* wsT = wsR + (size_t)8 * 64 * 16384;          // + 18,874,368 B
    hipLaunchKernelGGL(pack_k, dim3(512), dim3(256), 0, stream, K, wsR, wsT);
    hipLaunchKernelGGL(attn_fa, dim3(512), dim3(256), 0, stream, Q, wsR, wsT, O);
}